// Round 1
// baseline (1730.373 us; speedup 1.0000x reference)
//
#include <hip/hip_runtime.h>
#include <math.h>

#define IMGS 16
#define EMB 2400
#define HW 196
#define CAPS 64
#define ATTK 180
#define NPOOL 15
#define NCOLS (IMGS * HW)  // 3136

// ---------------- Weldon pooling: top15 + bottom15 mean per (img, emb) ----------------
__global__ void weldon_kernel(const float* __restrict__ g, float* __restrict__ hpool) {
    int r = blockIdx.x * blockDim.x + threadIdx.x;
    if (r >= IMGS * EMB) return;
    const float* row = g + (size_t)r * HW;  // g[i][e][hw], r = i*EMB+e
    float t[NPOOL], b[NPOOL];
#pragma unroll
    for (int j = 0; j < NPOOL; j++) { t[j] = -INFINITY; b[j] = INFINITY; }
    for (int hw = 0; hw < HW; hw++) {
        float v = row[hw];
        if (v > t[0]) {
            t[0] = v;
#pragma unroll
            for (int j = 0; j < NPOOL - 1; j++) {
                if (t[j] > t[j + 1]) { float tmp = t[j]; t[j] = t[j + 1]; t[j + 1] = tmp; }
            }
        }
        if (v < b[0]) {
            b[0] = v;
#pragma unroll
            for (int j = 0; j < NPOOL - 1; j++) {
                if (b[j] < b[j + 1]) { float tmp = b[j]; b[j] = b[j + 1]; b[j + 1] = tmp; }
            }
        }
    }
    float st = 0.f, sb = 0.f;
#pragma unroll
    for (int j = 0; j < NPOOL; j++) { st += t[j]; sb += b[j]; }
    hpool[r] = st / 15.0f + sb / 15.0f;
}

// ---------------- x = hpool @ fc_w.T + fc_b  (one 64-lane block per output column o) ----------------
__global__ void x_kernel(const float* __restrict__ hpool, const float* __restrict__ fc_w,
                         const float* __restrict__ fc_b, float* __restrict__ x_out) {
    int o = blockIdx.x;
    int lane = threadIdx.x;  // 64
    float acc[IMGS];
#pragma unroll
    for (int i = 0; i < IMGS; i++) acc[i] = 0.f;
    const float* wrow = fc_w + (size_t)o * EMB;
    for (int e = lane; e < EMB; e += 64) {
        float wv = wrow[e];
#pragma unroll
        for (int i = 0; i < IMGS; i++) acc[i] += hpool[i * EMB + e] * wv;
    }
#pragma unroll
    for (int i = 0; i < IMGS; i++) {
#pragma unroll
        for (int s = 32; s > 0; s >>= 1) acc[i] += __shfl_xor(acc[i], s, 64);
    }
    if (lane == 0) {
        float bo = fc_b[o];
#pragma unroll
        for (int i = 0; i < IMGS; i++) x_out[i * EMB + o] = acc[i] + bo;
    }
}

// ---------------- exact top-180 per caption via rank counting (stable argsort order) ----------------
__global__ void topk_kernel(const float* __restrict__ caps, int* __restrict__ idxs,
                            float* __restrict__ vals) {
    __shared__ float row[EMB];
    int c = blockIdx.x;
    int tid = threadIdx.x;  // 256
    for (int e = tid; e < EMB; e += 256) row[e] = caps[(size_t)c * EMB + e];
    __syncthreads();
    float v[10];
    int cnt[10];
#pragma unroll
    for (int s = 0; s < 10; s++) {
        int e = tid + s * 256;
        v[s] = (e < EMB) ? row[e] : -INFINITY;
        cnt[s] = 0;
    }
    for (int j = 0; j < EMB; j++) {
        float vj = row[j];
#pragma unroll
        for (int s = 0; s < 10; s++) {
            int e = tid + s * 256;
            cnt[s] += (vj > v[s]) || (vj == v[s] && j < e);
        }
    }
#pragma unroll
    for (int s = 0; s < 10; s++) {
        int e = tid + s * 256;
        if (e < EMB && cnt[s] < ATTK) {
            idxs[c * ATTK + cnt[s]] = e;
            vals[c * ATTK + cnt[s]] = fabsf(v[s]);
        }
    }
}

// ---------------- GEMM1: A_out[o, n] = | sum_e fc_w[o,e] * g[i(n), e, hw(n)] |  ----------------
// M=2400 (25x96), N=3136 (49x64), K=2400 (150x16). 256 thr, 6x4 micro.
__global__ __launch_bounds__(256) void gemm1_kernel(const float* __restrict__ fc_w,
                                                    const float* __restrict__ g,
                                                    float* __restrict__ A_out) {
    __shared__ float As[16][96 + 1];  // [k][m]
    __shared__ float Bs[16][64];      // [k][n]
    int m0 = blockIdx.y * 96;
    int n0 = blockIdx.x * 64;
    int tid = threadIdx.x;
    int tm = tid / 16;  // 0..15
    int tn = tid % 16;  // 0..15
    float acc[6][4] = {};
    for (int k0 = 0; k0 < EMB; k0 += 16) {
#pragma unroll
        for (int l = 0; l < 6; l++) {
            int flat = tid + l * 256;
            int el = flat % 16, ol = flat / 16;
            As[el][ol] = fc_w[(size_t)(m0 + ol) * EMB + k0 + el];
        }
#pragma unroll
        for (int l = 0; l < 4; l++) {
            int flat = tid + l * 256;
            int nl = flat % 64, kl = flat / 64;
            int n = n0 + nl;
            int i = n / HW, hw = n % HW;
            Bs[kl][nl] = g[(size_t)i * EMB * HW + (size_t)(k0 + kl) * HW + hw];
        }
        __syncthreads();
#pragma unroll
        for (int k = 0; k < 16; k++) {
            float a[6], b[4];
#pragma unroll
            for (int j = 0; j < 6; j++) a[j] = As[k][tm * 6 + j];
#pragma unroll
            for (int j = 0; j < 4; j++) b[j] = Bs[k][tn * 4 + j];
#pragma unroll
            for (int x_ = 0; x_ < 6; x_++)
#pragma unroll
                for (int y_ = 0; y_ < 4; y_++) acc[x_][y_] += a[x_] * b[y_];
        }
        __syncthreads();
    }
#pragma unroll
    for (int x_ = 0; x_ < 6; x_++) {
        int m = m0 + tm * 6 + x_;
#pragma unroll
        for (int y_ = 0; y_ < 4; y_++) {
            int n = n0 + tn * 4 + y_;
            A_out[(size_t)m * NCOLS + n] = fabsf(acc[x_][y_]);
        }
    }
}

// ---------------- heat: H[c, n] = sum_j vals[c,j] * A[idx[c,j], n]  (sparse 180-term) ----------------
__global__ void heat_kernel(const int* __restrict__ idxs, const float* __restrict__ vals,
                            const float* __restrict__ A, float* __restrict__ H) {
    __shared__ int sidx[ATTK];
    __shared__ float sval[ATTK];
    int c = blockIdx.y;
    int tid = threadIdx.x;
    if (tid < ATTK) {
        sidx[tid] = idxs[c * ATTK + tid];
        sval[tid] = vals[c * ATTK + tid];
    }
    __syncthreads();
    int n = blockIdx.x * 256 + tid;
    if (n >= NCOLS) return;
    float acc = 0.f;
    for (int j = 0; j < ATTK; j++) acc += sval[j] * A[(size_t)sidx[j] * NCOLS + n];
    H[(size_t)c * NCOLS + n] = acc;
}

// ---------------- normalize per (c, i) over hw ----------------
__global__ void norm_kernel(float* __restrict__ H) {
    int c = blockIdx.x / IMGS, i = blockIdx.x % IMGS;
    float* p = H + (size_t)c * NCOLS + i * HW;
    int lane = threadIdx.x;  // 64
    float s = 0.f;
    for (int hw = lane; hw < HW; hw += 64) s += p[hw];
#pragma unroll
    for (int d = 32; d > 0; d >>= 1) s += __shfl_xor(s, d, 64);
    float inv = 1.0f / s;
    for (int hw = lane; hw < HW; hw += 64) p[hw] *= inv;
}

// ---------------- xa_pre[i, c, e] = sum_hw Hn[c, i*196+hw] * g[i, e, hw] ----------------
// grid (eh=2, cg=8, i=16), block 256; 8 captions per block staged in LDS.
__global__ void xapre_kernel(const float* __restrict__ H, const float* __restrict__ g,
                             float* __restrict__ P) {
    __shared__ float h[8][HW];
    int i = blockIdx.z;
    int c0 = blockIdx.y * 8;
    int e0 = blockIdx.x * 1200;
    int tid = threadIdx.x;
    for (int flat = tid; flat < 8 * HW; flat += 256) {
        int cl = flat / HW, hw = flat % HW;
        h[cl][hw] = H[(size_t)(c0 + cl) * NCOLS + i * HW + hw];
    }
    __syncthreads();
    for (int l = 0; l < 5; l++) {
        int off = l * 256 + tid;
        if (off >= 1200) break;
        int e = e0 + off;
        float acc[8] = {};
        const float4* grow = (const float4*)(g + (size_t)i * EMB * HW + (size_t)e * HW);
        for (int q = 0; q < HW / 4; q++) {
            float4 g4 = grow[q];
#pragma unroll
            for (int cl = 0; cl < 8; cl++) {
                acc[cl] += h[cl][4 * q + 0] * g4.x + h[cl][4 * q + 1] * g4.y +
                           h[cl][4 * q + 2] * g4.z + h[cl][4 * q + 3] * g4.w;
            }
        }
#pragma unroll
        for (int cl = 0; cl < 8; cl++)
            P[((size_t)i * CAPS + c0 + cl) * EMB + e] = acc[cl];
    }
}

// ---------------- GEMM3 (NT): out[m, o] = sum_e P[m,e]*fc_w[o,e] + fc_b[o] ----------------
// M=1024 (16x64), N=2400 (25x96), K=2400. 256 thr, 4x6 micro.
__global__ __launch_bounds__(256) void gemm3_kernel(const float* __restrict__ P,
                                                    const float* __restrict__ fc_w,
                                                    const float* __restrict__ fc_b,
                                                    float* __restrict__ out) {
    __shared__ float As[16][64 + 1];
    __shared__ float Bs[16][96 + 1];
    int m0 = blockIdx.y * 64;
    int n0 = blockIdx.x * 96;
    int tid = threadIdx.x;
    int tm = tid / 16, tn = tid % 16;
    float acc[4][6] = {};
    for (int k0 = 0; k0 < EMB; k0 += 16) {
#pragma unroll
        for (int l = 0; l < 4; l++) {
            int flat = tid + l * 256;
            int el = flat % 16, ml = flat / 16;
            As[el][ml] = P[(size_t)(m0 + ml) * EMB + k0 + el];
        }
#pragma unroll
        for (int l = 0; l < 6; l++) {
            int flat = tid + l * 256;
            int el = flat % 16, nl = flat / 16;
            Bs[el][nl] = fc_w[(size_t)(n0 + nl) * EMB + k0 + el];
        }
        __syncthreads();
#pragma unroll
        for (int k = 0; k < 16; k++) {
            float a[4], b[6];
#pragma unroll
            for (int j = 0; j < 4; j++) a[j] = As[k][tm * 4 + j];
#pragma unroll
            for (int j = 0; j < 6; j++) b[j] = Bs[k][tn * 6 + j];
#pragma unroll
            for (int x_ = 0; x_ < 4; x_++)
#pragma unroll
                for (int y_ = 0; y_ < 6; y_++) acc[x_][y_] += a[x_] * b[y_];
        }
        __syncthreads();
    }
#pragma unroll
    for (int x_ = 0; x_ < 4; x_++) {
        int m = m0 + tm * 4 + x_;
#pragma unroll
        for (int y_ = 0; y_ < 6; y_++) {
            int n = n0 + tn * 6 + y_;
            out[(size_t)m * EMB + n] = acc[x_][y_] + fc_b[n];
        }
    }
}

extern "C" void kernel_launch(void* const* d_in, const int* in_sizes, int n_in,
                              void* d_out, int out_size, void* d_ws, size_t ws_size,
                              hipStream_t stream) {
    const float* g = (const float*)d_in[0];
    const float* caps = (const float*)d_in[1];
    const float* fc_w = (const float*)d_in[2];
    const float* fc_b = (const float*)d_in[3];

    float* out = (float*)d_out;
    float* x_out = out;                        // 16*2400 = 38400
    float* xa_out = out + 38400;               // 16*64*2400 = 2457600
    float* g_out = out + 38400 + 2457600;      // 7526400
    float* A = g_out;                          // scratch: |gf| [2400][3136], overwritten by g later

    float* ws = (float*)d_ws;
    float* hpool = ws;                  // 38400
    int* idxs = (int*)(ws + 38400);     // 64*180 = 11520
    float* vals = ws + 49920;           // 11520
    float* H = ws + 61440;              // 64*3136 = 200704
    float* P = ws + 262144;             // 2457600  (total 10.88 MB)

    weldon_kernel<<<(IMGS * EMB) / 256, 256, 0, stream>>>(g, hpool);
    x_kernel<<<EMB, 64, 0, stream>>>(hpool, fc_w, fc_b, x_out);
    topk_kernel<<<CAPS, 256, 0, stream>>>(caps, idxs, vals);
    gemm1_kernel<<<dim3(NCOLS / 64, EMB / 96), 256, 0, stream>>>(fc_w, g, A);
    heat_kernel<<<dim3((NCOLS + 255) / 256, CAPS), 256, 0, stream>>>(idxs, vals, A, H);
    norm_kernel<<<CAPS * IMGS, 64, 0, stream>>>(H);
    // g passthrough: safe to overwrite A after heat_kernel (stream-ordered)
    hipMemcpyAsync(g_out, g, sizeof(float) * (size_t)IMGS * EMB * HW,
                   hipMemcpyDeviceToDevice, stream);
    xapre_kernel<<<dim3(2, 8, IMGS), 256, 0, stream>>>(H, g, P);
    gemm3_kernel<<<dim3(EMB / 96, (IMGS * CAPS) / 64), 256, 0, stream>>>(P, fc_w, fc_b, xa_out);
}

// Round 2
// 605.671 us; speedup vs baseline: 2.8570x; 2.8570x over previous
//
#include <hip/hip_runtime.h>
#include <math.h>

#define IMGS 16
#define EMB 2400
#define HW 196
#define CAPS 64
#define ATTK 180
#define NPOOL 15
#define NCOLS (IMGS * HW)  // 3136

typedef __attribute__((ext_vector_type(8))) short short8;
typedef __attribute__((ext_vector_type(4))) float f32x4;

__device__ inline unsigned short f2bf(float f) {
    unsigned int u = __builtin_bit_cast(unsigned int, f);
    u += 0x7fffu + ((u >> 16) & 1u);  // round-to-nearest-even
    return (unsigned short)(u >> 16);
}
__device__ inline float bf2f(unsigned int lo16) {
    return __builtin_bit_cast(float, lo16 << 16);
}

// ---------------- Weldon pooling: top15 + bottom15 mean per (img, emb) ----------------
__global__ void weldon_kernel(const float* __restrict__ g, float* __restrict__ hpool) {
    int r = blockIdx.x * blockDim.x + threadIdx.x;
    if (r >= IMGS * EMB) return;
    const float* row = g + (size_t)r * HW;
    float t[NPOOL], b[NPOOL];
#pragma unroll
    for (int j = 0; j < NPOOL; j++) { t[j] = -INFINITY; b[j] = INFINITY; }
    for (int hw = 0; hw < HW; hw++) {
        float v = row[hw];
        if (v > t[0]) {
            t[0] = v;
#pragma unroll
            for (int j = 0; j < NPOOL - 1; j++) {
                if (t[j] > t[j + 1]) { float tmp = t[j]; t[j] = t[j + 1]; t[j + 1] = tmp; }
            }
        }
        if (v < b[0]) {
            b[0] = v;
#pragma unroll
            for (int j = 0; j < NPOOL - 1; j++) {
                if (b[j] < b[j + 1]) { float tmp = b[j]; b[j] = b[j + 1]; b[j + 1] = tmp; }
            }
        }
    }
    float st = 0.f, sb = 0.f;
#pragma unroll
    for (int j = 0; j < NPOOL; j++) { st += t[j]; sb += b[j]; }
    hpool[r] = st / 15.0f + sb / 15.0f;
}

// ---------------- x = hpool @ fc_w.T + fc_b ----------------
__global__ void x_kernel(const float* __restrict__ hpool, const float* __restrict__ fc_w,
                         const float* __restrict__ fc_b, float* __restrict__ x_out) {
    int o = blockIdx.x;
    int lane = threadIdx.x;  // 64
    float acc[IMGS];
#pragma unroll
    for (int i = 0; i < IMGS; i++) acc[i] = 0.f;
    const float* wrow = fc_w + (size_t)o * EMB;
    for (int e = lane; e < EMB; e += 64) {
        float wv = wrow[e];
#pragma unroll
        for (int i = 0; i < IMGS; i++) acc[i] += hpool[i * EMB + e] * wv;
    }
#pragma unroll
    for (int i = 0; i < IMGS; i++) {
#pragma unroll
        for (int s = 32; s > 0; s >>= 1) acc[i] += __shfl_xor(acc[i], s, 64);
    }
    if (lane == 0) {
        float bo = fc_b[o];
#pragma unroll
        for (int i = 0; i < IMGS; i++) x_out[i * EMB + o] = acc[i] + bo;
    }
}

// ---------------- top-180 per caption, rank-count, parallel over e ----------------
// grid (10 chunks, CAPS), block 256. Thread owns e = chunk*256+tid; counts rank over LDS row.
__global__ void topk_kernel(const float* __restrict__ caps, int* __restrict__ idxs,
                            float* __restrict__ vals) {
    __shared__ float row[EMB];
    int c = blockIdx.y;
    int tid = threadIdx.x;
    for (int e = tid; e < EMB; e += 256) row[e] = caps[(size_t)c * EMB + e];
    __syncthreads();
    int e = blockIdx.x * 256 + tid;
    if (e >= EMB) return;
    float v = row[e];
    int cnt = 0;
    for (int j = 0; j < EMB; j += 4) {
        float4 q = *(const float4*)&row[j];
        cnt += (q.x > v) || (q.x == v && (j + 0) < e);
        cnt += (q.y > v) || (q.y == v && (j + 1) < e);
        cnt += (q.z > v) || (q.z == v && (j + 2) < e);
        cnt += (q.w > v) || (q.w == v && (j + 3) < e);
    }
    if (cnt < ATTK) {
        idxs[c * ATTK + cnt] = e;
        vals[c * ATTK + cnt] = fabsf(v);
    }
}

// ---------------- fc_w fp32 -> bf16 row-major copy ----------------
__global__ void convert_w_kernel(const float* __restrict__ w, unsigned short* __restrict__ wbf) {
    int i = (blockIdx.x * 256 + threadIdx.x) * 4;
    if (i >= EMB * EMB) return;
    float4 a = *(const float4*)&w[i];
    ushort4 r;
    r.x = f2bf(a.x); r.y = f2bf(a.y); r.z = f2bf(a.z); r.w = f2bf(a.w);
    *(ushort4*)&wbf[i] = r;
}

// ---------------- gT[n][e] = bf16(g[i(n)][e][hw(n)]), n = i*196+hw ----------------
// grid (4 hw-chunks of 49, 25 e-chunks of 96, 16 imgs), block 256
__global__ void transpose_g_kernel(const float* __restrict__ g, unsigned short* __restrict__ gT) {
    __shared__ float t[96][50];
    int i = blockIdx.z;
    int e0 = blockIdx.y * 96;
    int h0 = blockIdx.x * 49;
    int tid = threadIdx.x;
    for (int f = tid; f < 96 * 49; f += 256) {
        int e = f / 49, hh = f % 49;
        t[e][hh] = g[(size_t)i * EMB * HW + (size_t)(e0 + e) * HW + h0 + hh];
    }
    __syncthreads();
    for (int f = tid; f < 49 * 96; f += 256) {
        int hh = f / 96, e = f % 96;
        gT[(size_t)(i * HW + h0 + hh) * EMB + e0 + e] = f2bf(t[e][hh]);
    }
}

// ---------------- staging loaders: 8 consecutive K-elems -> packed bf16x8 (uint4) ----------------
__device__ inline uint4 load8(const unsigned short* p) { return *(const uint4*)p; }
__device__ inline uint4 load8(const float* p) {
    float4 a = *(const float4*)p;
    float4 b = *(const float4*)(p + 4);
    uint4 r;
    r.x = (unsigned)f2bf(a.x) | ((unsigned)f2bf(a.y) << 16);
    r.y = (unsigned)f2bf(a.z) | ((unsigned)f2bf(a.w) << 16);
    r.z = (unsigned)f2bf(b.x) | ((unsigned)f2bf(b.y) << 16);
    r.w = (unsigned)f2bf(b.z) | ((unsigned)f2bf(b.w) << 16);
    return r;
}

// ---------------- NT bf16 MFMA GEMM: out[m][n] = sum_k A[m][k]*B[n][k] ----------------
// BM=MF*32, BN=NF*32; 4 waves in 2x2; per-wave MFxNF frags of 16x16, BK=32.
// ABS_OUT: write bf16 |v|; else write f32 v + bias[n].
template <int MF, int NF, bool ABS_OUT, typename TA, typename TB>
__global__ __launch_bounds__(256) void mfma_gemm_nt(const TA* __restrict__ A,
                                                    const TB* __restrict__ B,
                                                    const float* __restrict__ bias,
                                                    void* __restrict__ outp,
                                                    int M, int N, int K) {
    constexpr int BM = MF * 32, BN = NF * 32;
    __shared__ unsigned short As[BM][40];
    __shared__ unsigned short Bs[BN][40];
    int m0 = blockIdx.y * BM, n0 = blockIdx.x * BN;
    int tid = threadIdx.x;
    int w = tid >> 6, lane = tid & 63;
    int wm = (w >> 1) * (MF * 16), wn = (w & 1) * (NF * 16);
    int ln = lane & 15, ks = (lane >> 4) * 8;
    f32x4 acc[MF][NF] = {};
    constexpr int nA = BM * 4, nB = BN * 4;
    for (int k0 = 0; k0 < K; k0 += 32) {
        for (int c = tid; c < nA + nB; c += 256) {
            if (c < nA) {
                int row = c >> 2, kc = c & 3;
                *(uint4*)&As[row][kc * 8] = load8(A + (size_t)(m0 + row) * K + k0 + kc * 8);
            } else {
                int cc = c - nA;
                int row = cc >> 2, kc = cc & 3;
                *(uint4*)&Bs[row][kc * 8] = load8(B + (size_t)(n0 + row) * K + k0 + kc * 8);
            }
        }
        __syncthreads();
        short8 af[MF], bfv[NF];
#pragma unroll
        for (int mf = 0; mf < MF; mf++)
            af[mf] = *(const short8*)&As[wm + mf * 16 + ln][ks];
#pragma unroll
        for (int nf = 0; nf < NF; nf++)
            bfv[nf] = *(const short8*)&Bs[wn + nf * 16 + ln][ks];
#pragma unroll
        for (int mf = 0; mf < MF; mf++)
#pragma unroll
            for (int nf = 0; nf < NF; nf++)
                acc[mf][nf] = __builtin_amdgcn_mfma_f32_16x16x32_bf16(af[mf], bfv[nf],
                                                                      acc[mf][nf], 0, 0, 0);
        __syncthreads();
    }
#pragma unroll
    for (int mf = 0; mf < MF; mf++) {
#pragma unroll
        for (int nf = 0; nf < NF; nf++) {
#pragma unroll
            for (int r = 0; r < 4; r++) {
                int row = m0 + wm + mf * 16 + (lane >> 4) * 4 + r;
                int col = n0 + wn + nf * 16 + ln;
                float v = acc[mf][nf][r];
                if (ABS_OUT) {
                    ((unsigned short*)outp)[(size_t)row * N + col] = f2bf(fabsf(v));
                } else {
                    ((float*)outp)[(size_t)row * N + col] = v + bias[col];
                }
            }
        }
    }
}

// ---------------- heat: H[c,n] = sum_j vals[c,j] * Abf[idx[c,j], n], 2 cols/thread ----------------
__global__ void heat_kernel(const int* __restrict__ idxs, const float* __restrict__ vals,
                            const unsigned short* __restrict__ A, float* __restrict__ H) {
    __shared__ int sidx[ATTK];
    __shared__ float sval[ATTK];
    int c = blockIdx.y;
    int tid = threadIdx.x;
    if (tid < ATTK) {
        sidx[tid] = idxs[c * ATTK + tid];
        sval[tid] = vals[c * ATTK + tid];
    }
    __syncthreads();
    int n = (blockIdx.x * 256 + tid) * 2;
    if (n >= NCOLS) return;
    float a0 = 0.f, a1 = 0.f;
    for (int j = 0; j < ATTK; j++) {
        unsigned int p = *(const unsigned int*)&A[(size_t)sidx[j] * NCOLS + n];
        a0 += sval[j] * bf2f(p & 0xffffu);
        a1 += sval[j] * bf2f(p >> 16);
    }
    H[(size_t)c * NCOLS + n] = a0;
    H[(size_t)c * NCOLS + n + 1] = a1;
}

// ---------------- normalize per (c, i) over hw ----------------
__global__ void norm_kernel(float* __restrict__ H) {
    int c = blockIdx.x / IMGS, i = blockIdx.x % IMGS;
    float* p = H + (size_t)c * NCOLS + i * HW;
    int lane = threadIdx.x;
    float s = 0.f;
    for (int hw = lane; hw < HW; hw += 64) s += p[hw];
#pragma unroll
    for (int d = 32; d > 0; d >>= 1) s += __shfl_xor(s, d, 64);
    float inv = 1.0f / s;
    for (int hw = lane; hw < HW; hw += 64) p[hw] *= inv;
}

// ---------------- xa_pre[i, c, e] = sum_hw Hn[c, i*196+hw] * g[i, e, hw] -> bf16 ----------------
__global__ void xapre_kernel(const float* __restrict__ H, const float* __restrict__ g,
                             unsigned short* __restrict__ P) {
    __shared__ float h[8][HW];
    int i = blockIdx.z;
    int c0 = blockIdx.y * 8;
    int e0 = blockIdx.x * 1200;
    int tid = threadIdx.x;
    for (int flat = tid; flat < 8 * HW; flat += 256) {
        int cl = flat / HW, hw = flat % HW;
        h[cl][hw] = H[(size_t)(c0 + cl) * NCOLS + i * HW + hw];
    }
    __syncthreads();
    for (int l = 0; l < 5; l++) {
        int off = l * 256 + tid;
        if (off >= 1200) break;
        int e = e0 + off;
        float acc[8] = {};
        const float4* grow = (const float4*)(g + (size_t)i * EMB * HW + (size_t)e * HW);
        for (int q = 0; q < HW / 4; q++) {
            float4 g4 = grow[q];
#pragma unroll
            for (int cl = 0; cl < 8; cl++) {
                acc[cl] += h[cl][4 * q + 0] * g4.x + h[cl][4 * q + 1] * g4.y +
                           h[cl][4 * q + 2] * g4.z + h[cl][4 * q + 3] * g4.w;
            }
        }
#pragma unroll
        for (int cl = 0; cl < 8; cl++)
            P[((size_t)i * CAPS + c0 + cl) * EMB + e] = f2bf(acc[cl]);
    }
}

extern "C" void kernel_launch(void* const* d_in, const int* in_sizes, int n_in,
                              void* d_out, int out_size, void* d_ws, size_t ws_size,
                              hipStream_t stream) {
    const float* g = (const float*)d_in[0];
    const float* caps = (const float*)d_in[1];
    const float* fc_w = (const float*)d_in[2];
    const float* fc_b = (const float*)d_in[3];

    float* out = (float*)d_out;
    float* x_out = out;                    // 38400
    float* xa_out = out + 38400;           // 2457600
    float* g_out = out + 38400 + 2457600;  // 7526400 floats
    // g_out region reused as scratch until the final passthrough copy:
    unsigned short* Abf = (unsigned short*)g_out;       // |gf| bf16 [2400][3136] = 15.05 MB
    unsigned short* gT = Abf + (size_t)EMB * NCOLS;     // bf16 [3136][2400] = 15.05 MB (exact fit)

    float* ws = (float*)d_ws;
    float* hpool = ws;                           // 38400
    int* idxs = (int*)(ws + 38400);              // 11520
    float* vals = ws + 49920;                    // 11520
    float* H = ws + 61440;                       // 200704
    unsigned short* Pbf = (unsigned short*)(ws + 262144);  // 2457600 ushort (ends at byte 5,963,776)
    unsigned short* wbf = (unsigned short*)(ws + 1490944); // 5760000 ushort (ends at byte 17,483,776)
    bool use_wbf = ws_size >= (size_t)17483776;

    weldon_kernel<<<(IMGS * EMB) / 256, 256, 0, stream>>>(g, hpool);
    x_kernel<<<EMB, 64, 0, stream>>>(hpool, fc_w, fc_b, x_out);
    topk_kernel<<<dim3(10, CAPS), 256, 0, stream>>>(caps, idxs, vals);
    transpose_g_kernel<<<dim3(4, 25, IMGS), 256, 0, stream>>>(g, gT);

    if (use_wbf) {
        convert_w_kernel<<<(EMB * EMB / 4 + 255) / 256, 256, 0, stream>>>(fc_w, wbf);
        mfma_gemm_nt<3, 2, true, unsigned short, unsigned short>
            <<<dim3(NCOLS / 64, EMB / 96), 256, 0, stream>>>(wbf, gT, nullptr, Abf,
                                                             EMB, NCOLS, EMB);
    } else {
        mfma_gemm_nt<3, 2, true, float, unsigned short>
            <<<dim3(NCOLS / 64, EMB / 96), 256, 0, stream>>>(fc_w, gT, nullptr, Abf,
                                                             EMB, NCOLS, EMB);
    }
    heat_kernel<<<dim3((NCOLS / 2 + 255) / 256, CAPS), 256, 0, stream>>>(idxs, vals, Abf, H);
    norm_kernel<<<CAPS * IMGS, 64, 0, stream>>>(H);
    // g passthrough (overwrites Abf+gT; both dead after heat/gemm1)
    hipMemcpyAsync(g_out, g, sizeof(float) * (size_t)IMGS * EMB * HW,
                   hipMemcpyDeviceToDevice, stream);
    xapre_kernel<<<dim3(2, 8, IMGS), 256, 0, stream>>>(H, g, Pbf);
    if (use_wbf) {
        mfma_gemm_nt<2, 3, false, unsigned short, unsigned short>
            <<<dim3(EMB / 96, (IMGS * CAPS) / 64), 256, 0, stream>>>(Pbf, wbf, fc_b, xa_out,
                                                                     IMGS * CAPS, EMB, EMB);
    } else {
        mfma_gemm_nt<2, 3, false, unsigned short, float>
            <<<dim3(EMB / 96, (IMGS * CAPS) / 64), 256, 0, stream>>>(Pbf, fc_w, fc_b, xa_out,
                                                                     IMGS * CAPS, EMB, EMB);
    }
}